// Round 4
// baseline (751.663 us; speedup 1.0000x reference)
//
#include <hip/hip_runtime.h>

#define DI __device__ __forceinline__

typedef __attribute__((ext_vector_type(8))) short short8;
typedef __attribute__((ext_vector_type(4))) float floatx4;
typedef unsigned short u16;

// ---- constants ----
#define Bb 2
#define Tt 2048
#define Cc 1024
#define Hh 16
#define Dd 64
// base-2 softmax: s2 = (q.k) * (1/sqrt(64)) * log2(e)
#define C1 0.1803368801111244f
#define NEGBIG (-1e30f)

DI float bf2f(u16 u) { union { unsigned int i; float f; } v; v.i = ((unsigned int)u) << 16; return v.f; }
DI u16 f2bf(float f) {
  union { float f; unsigned int i; } v; v.f = f;
  unsigned int i = v.i;
  unsigned int r = i + 0x7fffu + ((i >> 16) & 1u);  // RNE
  return (u16)(r >> 16);
}

DI floatx4 mfma16(short8 a, short8 b, floatx4 c) {
  return __builtin_amdgcn_mfma_f32_16x16x32_bf16(a, b, c, 0, 0, 0);
}

// async global->LDS, 16B per lane. LDS dest = wave-uniform base + lane*16 (linear!).
DI void gload16(const u16* g, u16* l) {
  __builtin_amdgcn_global_load_lds(
      (const __attribute__((address_space(1))) unsigned int*)(g),
      (__attribute__((address_space(3))) unsigned int*)(l), 16, 0, 0);
}

// load 8 consecutive elements (element offset eoff) as 8 bf16 packed in uint4
DI uint4 load8(const void* p, size_t eoff, int isbf) {
  if (isbf) {
    return *(const uint4*)((const u16*)p + eoff);
  } else {
    const float* f = (const float*)p + eoff;
    float4 a = *(const float4*)f;
    float4 b = *(const float4*)(f + 4);
    union { uint4 u; u16 s[8]; } r;
    r.s[0] = f2bf(a.x); r.s[1] = f2bf(a.y); r.s[2] = f2bf(a.z); r.s[3] = f2bf(a.w);
    r.s[4] = f2bf(b.x); r.s[5] = f2bf(b.y); r.s[6] = f2bf(b.z); r.s[7] = f2bf(b.w);
    return r.u;
  }
}

DI float loadb(const void* p, int i, int isbf) {
  return isbf ? bf2f(((const u16*)p)[i]) : ((const float*)p)[i];
}

// ============================================================
// dtype detector (inputs only): sample even u16 indices of x.
// ============================================================
__global__ void detect_dtype(const u16* __restrict__ x, int* __restrict__ flag) {
  __shared__ int cnt[256];
  int c = 0;
  for (int i = threadIdx.x; i < 4096; i += 256) {
    unsigned u = x[2 * i];
    unsigned e = (u >> 7) & 0xFFu;
    c += (e == 0u || (e >= 100u && e <= 150u)) ? 1 : 0;
  }
  cnt[threadIdx.x] = c;
  __syncthreads();
  for (int s = 128; s > 0; s >>= 1) {
    if ((int)threadIdx.x < s) cnt[threadIdx.x] += cnt[threadIdx.x + s];
    __syncthreads();
  }
  if (threadIdx.x == 0) *flag = (cnt[0] > 2458) ? 1 : 0;
}

// ============================================================
// one-shot convert to bf16 workspace: X (4.19M), Wq/Wk/Wv/Wo (1.05M each)
// ============================================================
__global__ __launch_bounds__(256) void convert_all(
    const void* __restrict__ x,
    const void* __restrict__ wq, const void* __restrict__ wk,
    const void* __restrict__ wv, const void* __restrict__ wo,
    u16* __restrict__ xb,
    u16* __restrict__ wqb, u16* __restrict__ wkb,
    u16* __restrict__ wvb, u16* __restrict__ wob,
    const int* __restrict__ flagp) {
  const int isbf = *flagp;
  const void* src;
  u16* dst;
  size_t n;
  switch (blockIdx.y) {
    case 0: src = x;  dst = xb;  n = (size_t)Bb * Tt * Cc; break;
    case 1: src = wq; dst = wqb; n = (size_t)Cc * Cc; break;
    case 2: src = wk; dst = wkb; n = (size_t)Cc * Cc; break;
    case 3: src = wv; dst = wvb; n = (size_t)Cc * Cc; break;
    default: src = wo; dst = wob; n = (size_t)Cc * Cc; break;
  }
  size_t i8 = ((size_t)blockIdx.x * 256 + threadIdx.x) * 8;
  size_t step = (size_t)gridDim.x * 256 * 8;
  for (; i8 < n; i8 += step) {
    uint4 v = load8(src, i8, isbf);
    *(uint4*)(dst + i8) = v;
  }
}

// ============================================================
// GEMM-BT (m97 structure): Out[m,n] = sum_k A[m,k] * W[n,k] + bias[n]
// ============================================================
__global__ __launch_bounds__(256) void qkv_gemm(
    const u16* __restrict__ Xb,
    const u16* __restrict__ Wqb, const u16* __restrict__ Wkb, const u16* __restrict__ Wvb,
    const void* __restrict__ bq, const void* __restrict__ bk, const void* __restrict__ bv,
    u16* __restrict__ Qb, u16* __restrict__ Kb, u16* __restrict__ Vb,
    const int* __restrict__ flagp) {
  __shared__ __align__(16) u16 As[128 * 32];
  __shared__ __align__(16) u16 Bs[128 * 32];
  const int isbf = *flagp;
  const int z = blockIdx.z;
  const u16* W = (z == 0) ? Wqb : (z == 1) ? Wkb : Wvb;
  const void* bias = (z == 0) ? bq : (z == 1) ? bk : bv;
  u16* Out = (z == 0) ? Qb : (z == 1) ? Kb : Vb;

  const int m0 = blockIdx.y * 128, n0 = blockIdx.x * 128;
  const int tid = threadIdx.x;
  const int w = tid >> 6, lane = tid & 63, quad = lane >> 4, l15 = lane & 15;
  const int wm = w >> 1, wn = w & 1;

  floatx4 acc[4][4];
#pragma unroll
  for (int a = 0; a < 4; ++a)
#pragma unroll
    for (int b2 = 0; b2 < 4; ++b2) acc[a][b2] = (floatx4){0.f, 0.f, 0.f, 0.f};

  const int s0 = w * 128 + lane, s1 = s0 + 64;
  const int rA0 = s0 >> 2, c0 = (s0 & 3) * 8;
  const int rA1 = s1 >> 2, c1 = (s1 & 3) * 8;
  const u16* gA0 = Xb + (size_t)(m0 + rA0) * Cc + c0;
  const u16* gA1 = Xb + (size_t)(m0 + rA1) * Cc + c1;
  const u16* gB0 = W + (size_t)(n0 + rA0) * Cc + c0;
  const u16* gB1 = W + (size_t)(n0 + rA1) * Cc + c1;
  u16* lA0 = As + w * 1024;
  u16* lA1 = As + w * 1024 + 512;
  u16* lB0 = Bs + w * 1024;
  u16* lB1 = Bs + w * 1024 + 512;

  for (int k0 = 0; k0 < Cc; k0 += 32) {
    __syncthreads();
    gload16(gA0 + k0, lA0);
    gload16(gA1 + k0, lA1);
    gload16(gB0 + k0, lB0);
    gload16(gB1 + k0, lB1);
    __syncthreads();
    short8 af[4], bfv[4];
#pragma unroll
    for (int t = 0; t < 4; ++t)
      af[t] = *(const short8*)(As + (wm * 64 + t * 16 + l15) * 32 + quad * 8);
#pragma unroll
    for (int t = 0; t < 4; ++t)
      bfv[t] = *(const short8*)(Bs + (wn * 64 + t * 16 + l15) * 32 + quad * 8);
#pragma unroll
    for (int tm = 0; tm < 4; ++tm)
#pragma unroll
      for (int tn = 0; tn < 4; ++tn) acc[tm][tn] = mfma16(af[tm], bfv[tn], acc[tm][tn]);
  }

  float bb[4];
#pragma unroll
  for (int tn = 0; tn < 4; ++tn) bb[tn] = loadb(bias, n0 + wn * 64 + tn * 16 + l15, isbf);
#pragma unroll
  for (int tm = 0; tm < 4; ++tm) {
#pragma unroll
    for (int tn = 0; tn < 4; ++tn) {
      int n = n0 + wn * 64 + tn * 16 + l15;
      int h = n >> 6, d = n & 63;
#pragma unroll
      for (int r = 0; r < 4; ++r) {
        int m = m0 + wm * 64 + tm * 16 + quad * 4 + r;
        int b = m >> 11, t = m & 2047;
        Out[(((size_t)(b * Hh + h) * Tt) + t) * Dd + d] = f2bf(acc[tm][tn][r] + bb[tn]);
      }
    }
  }
}

// out-proj (m97 structure): fp32 output to d_out
__global__ __launch_bounds__(256) void out_gemm(
    const u16* __restrict__ Y, const u16* __restrict__ Wob, const void* __restrict__ bo,
    float* __restrict__ Out, const int* __restrict__ flagp) {
  __shared__ __align__(16) u16 As[128 * 32];
  __shared__ __align__(16) u16 Bs[128 * 32];
  const int isbf = *flagp;
  const int m0 = blockIdx.y * 128, n0 = blockIdx.x * 128;
  const int tid = threadIdx.x;
  const int w = tid >> 6, lane = tid & 63, quad = lane >> 4, l15 = lane & 15;
  const int wm = w >> 1, wn = w & 1;

  floatx4 acc[4][4];
#pragma unroll
  for (int a = 0; a < 4; ++a)
#pragma unroll
    for (int b2 = 0; b2 < 4; ++b2) acc[a][b2] = (floatx4){0.f, 0.f, 0.f, 0.f};

  const int s0 = w * 128 + lane, s1 = s0 + 64;
  const int rA0 = s0 >> 2, c0 = (s0 & 3) * 8;
  const int rA1 = s1 >> 2, c1 = (s1 & 3) * 8;
  const u16* gA0 = Y + (size_t)(m0 + rA0) * Cc + c0;
  const u16* gA1 = Y + (size_t)(m0 + rA1) * Cc + c1;
  const u16* gB0 = Wob + (size_t)(n0 + rA0) * Cc + c0;
  const u16* gB1 = Wob + (size_t)(n0 + rA1) * Cc + c1;
  u16* lA0 = As + w * 1024;
  u16* lA1 = As + w * 1024 + 512;
  u16* lB0 = Bs + w * 1024;
  u16* lB1 = Bs + w * 1024 + 512;

  for (int k0 = 0; k0 < Cc; k0 += 32) {
    __syncthreads();
    gload16(gA0 + k0, lA0);
    gload16(gA1 + k0, lA1);
    gload16(gB0 + k0, lB0);
    gload16(gB1 + k0, lB1);
    __syncthreads();
    short8 af[4], bfv[4];
#pragma unroll
    for (int t = 0; t < 4; ++t)
      af[t] = *(const short8*)(As + (wm * 64 + t * 16 + l15) * 32 + quad * 8);
#pragma unroll
    for (int t = 0; t < 4; ++t)
      bfv[t] = *(const short8*)(Bs + (wn * 64 + t * 16 + l15) * 32 + quad * 8);
#pragma unroll
    for (int tm = 0; tm < 4; ++tm)
#pragma unroll
      for (int tn = 0; tn < 4; ++tn) acc[tm][tn] = mfma16(af[tm], bfv[tn], acc[tm][tn]);
  }

  float bb[4];
#pragma unroll
  for (int tn = 0; tn < 4; ++tn) bb[tn] = loadb(bo, n0 + wn * 64 + tn * 16 + l15, isbf);
#pragma unroll
  for (int tm = 0; tm < 4; ++tm)
#pragma unroll
    for (int tn = 0; tn < 4; ++tn) {
      int n = n0 + wn * 64 + tn * 16 + l15;
#pragma unroll
      for (int r = 0; r < 4; ++r) {
        int m = m0 + wm * 64 + tm * 16 + quad * 4 + r;
        Out[(size_t)m * Cc + n] = acc[tm][tn][r] + bb[tn];
      }
    }
}

// ============================================================
// Attention v5: one WG (512 thr, 8 waves) per q-tile PAIR {z, 15-z}.
// K consumed DIRECTLY from global (L1/L2-resident; no K staging).
// Pass 1: no LDS, no barriers. Pass 2: only V in LDS, double-buffered,
// prefetched one block early, ONE __syncthreads per 128-key block.
// LDS: Vts[2][64][136] 34.8KB + Ps 10.2KB = 45 KB.
// ============================================================
__global__ __launch_bounds__(512) void attn_kernel(
    const u16* __restrict__ Qbuf, const u16* __restrict__ Kbuf, const u16* __restrict__ Vbuf,
    float* __restrict__ Att, u16* __restrict__ Ybuf) {
  __shared__ __align__(16) u16 Vts[2][64 * 136];
  __shared__ __align__(16) u16 Ps[8 * 16 * 40];

  const int id = blockIdx.x;
  const int zp = id >> 5;          // q-tile pair index 0..7
  const int hb = id & 31;          // (b,h)
  const int b = hb >> 4, h = hb & 15;

  const int tid = threadIdx.x;
  const int w = tid >> 6, lane = tid & 63, quad = lane >> 4, l15 = lane & 15;

  const size_t headoff = (size_t)(b * Hh + h) * Tt * Dd;
  const u16* Qh = Qbuf + headoff;
  const u16* Kh = Kbuf + headoff;
  const u16* Vh = Vbuf + headoff;
  float* attO = Att + (size_t)(b * Hh + h) * Tt * Tt;
  u16* Psw = Ps + w * 640;

  // per-lane K base: row l15 (within a 16-key tile), cols quad*8..+7
  const u16* Kl = Kh + (size_t)l15 * Dd + quad * 8;
  // V staging geometry: thread covers V row vrow, cols [vcb, vcb+16)
  const int vrow = tid >> 2, vcb = (tid & 3) * 16;

  for (int half = 0; half < 2; ++half) {
    const int qt = half ? (15 - zp) : zp;
    const int q0 = qt * 128;
    const int qw = q0 + w * 16;

    short8 aq0 = *(const short8*)(Qh + (size_t)(qw + l15) * Dd + quad * 8);
    short8 aq1 = *(const short8*)(Qh + (size_t)(qw + l15) * Dd + 32 + quad * 8);

    float m4[4], l4[4];
#pragma unroll
    for (int r = 0; r < 4; ++r) { m4[r] = NEGBIG; l4[r] = 0.f; }

    // ---------- pass 1: stats. No LDS, no barriers. ----------
    for (int c = 0; c <= qt; ++c) {
      const int kb = c * 128;
      floatx4 s[8];
#pragma unroll
      for (int kt = 0; kt < 8; ++kt) {
        const u16* kp = Kl + (size_t)(kb + kt * 16) * Dd;
        short8 b0 = *(const short8*)(kp);
        short8 b1 = *(const short8*)(kp + 32);
        floatx4 t = (floatx4){0.f, 0.f, 0.f, 0.f};
        t = mfma16(aq0, b0, t);
        t = mfma16(aq1, b1, t);
        s[kt] = t;
      }
      const bool partial = (kb + 127 > qw);
#pragma unroll
      for (int r = 0; r < 4; ++r) {
        const int qi = qw + quad * 4 + r;
        float e[8];
        float bm = NEGBIG;
#pragma unroll
        for (int kt = 0; kt < 8; ++kt) {
          float s2 = s[kt][r] * C1;
          if (partial) {
            int key = kb + kt * 16 + l15;
            s2 = (key <= qi) ? s2 : NEGBIG;
          }
          e[kt] = s2;
          bm = fmaxf(bm, s2);
        }
        float mn = fmaxf(m4[r], bm);
        float sum = 0.f;
#pragma unroll
        for (int kt = 0; kt < 8; ++kt) sum += exp2f(e[kt] - mn);
        l4[r] = l4[r] * exp2f(m4[r] - mn) + sum;
        m4[r] = mn;
      }
    }
    // merge (m,l) across the 16 lanes of each row group
#pragma unroll
    for (int r = 0; r < 4; ++r) {
      float m = m4[r], l = l4[r];
#pragma unroll
      for (int off = 1; off <= 8; off <<= 1) {
        float mo = __shfl_xor(m, off, 64);
        float lo = __shfl_xor(l, off, 64);
        float mn = fmaxf(m, mo);
        l = l * exp2f(m - mn) + lo * exp2f(mo - mn);
        m = mn;
      }
      m4[r] = m; l4[r] = l;
    }
    float lrec[4];
#pragma unroll
    for (int r = 0; r < 4; ++r) lrec[r] = 1.0f / l4[r];

    // ---------- pass 2: write att fp32, accumulate y ----------
    floatx4 yacc[4];
#pragma unroll
    for (int dt = 0; dt < 4; ++dt) yacc[dt] = (floatx4){0.f, 0.f, 0.f, 0.f};

    // V(0) prefetch into regs
    uint4 va = *(const uint4*)(Vh + (size_t)vrow * Dd + vcb);
    uint4 vb = *(const uint4*)(Vh + (size_t)vrow * Dd + vcb + 8);

    for (int c = 0; c <= qt; ++c) {
      const int kb = c * 128;
      u16* Vt = &Vts[c & 1][0];
      // write V(c) regs -> Vts[c&1]  (buffer's prior readers were iter c-2,
      // separated by iter c-1's barrier)
      {
        union { uint4 u; u16 sv[8]; } cv;
        cv.u = va;
#pragma unroll
        for (int j = 0; j < 8; ++j) Vt[(vcb + j) * 136 + vrow] = cv.sv[j];
        cv.u = vb;
#pragma unroll
        for (int j = 0; j < 8; ++j) Vt[(vcb + 8 + j) * 136 + vrow] = cv.sv[j];
      }
      // prefetch V(c+1) into regs (issued before QK: a full phase to land)
      if (c < qt) {
        va = *(const uint4*)(Vh + (size_t)(kb + 128 + vrow) * Dd + vcb);
        vb = *(const uint4*)(Vh + (size_t)(kb + 128 + vrow) * Dd + vcb + 8);
      }

      // QK directly from global
      floatx4 s[8];
#pragma unroll
      for (int kt = 0; kt < 8; ++kt) {
        const u16* kp = Kl + (size_t)(kb + kt * 16) * Dd;
        short8 b0 = *(const short8*)(kp);
        short8 b1 = *(const short8*)(kp + 32);
        floatx4 t = (floatx4){0.f, 0.f, 0.f, 0.f};
        t = mfma16(aq0, b0, t);
        t = mfma16(aq1, b1, t);
        s[kt] = t;
      }

      __syncthreads();   // Vts[c&1] writes visible to all waves

      const bool partial = (kb + 127 > qw);
#pragma unroll
      for (int ks = 0; ks < 4; ++ks) {
#pragma unroll
        for (int kk = 0; kk < 2; ++kk) {
          const int kt = ks * 2 + kk;
#pragma unroll
          for (int r = 0; r < 4; ++r) {
            const int row = quad * 4 + r;
            const int qi = qw + row;
            const int key = kb + kt * 16 + l15;
            float p = exp2f(fminf(s[kt][r] * C1 - m4[r], 0.f)) * lrec[r];
            if (partial && key > qi) p = 0.f;
            attO[(size_t)qi * Tt + key] = p;          // fp32 att output
            Psw[row * 40 + kk * 16 + l15] = f2bf(p);  // bf16 for PV MFMA
          }
        }
        short8 ap = *(const short8*)(Psw + l15 * 40 + quad * 8);
#pragma unroll
        for (int dt = 0; dt < 4; ++dt) {
          short8 bv = *(const short8*)(Vt + (dt * 16 + l15) * 136 + ks * 32 + quad * 8);
          yacc[dt] = mfma16(ap, bv, yacc[dt]);
        }
      }
    }

    // fully masked blocks: zero-fill (no barriers)
    {
      uint4 z; z.x = 0u; z.y = 0u; z.z = 0u; z.w = 0u;
      for (int c = qt + 1; c < 16; ++c) {
        const int kb = c * 128;
#pragma unroll
        for (int i = 0; i < 8; ++i) {
          int slot = tid + i * 512;
          int row = slot >> 5, g = slot & 31;
          *(uint4*)(attO + (size_t)(q0 + row) * Tt + kb + g * 4) = z;
        }
      }
    }

    // y epilogue: wave's 16 rows x 64 d
#pragma unroll
    for (int dt = 0; dt < 4; ++dt) {
#pragma unroll
      for (int r = 0; r < 4; ++r) {
        const int qi = qw + quad * 4 + r;
        Ybuf[(size_t)(b * Tt + qi) * Cc + h * Dd + dt * 16 + l15] = f2bf(yacc[dt][r]);
      }
    }
  }
}

extern "C" void kernel_launch(void* const* d_in, const int* in_sizes, int n_in,
                              void* d_out, int out_size, void* d_ws, size_t ws_size,
                              hipStream_t stream) {
  const void* x  = d_in[0];
  const void* Wq = d_in[1];
  const void* bq = d_in[2];
  const void* Wk = d_in[3];
  const void* bk = d_in[4];
  const void* Wv = d_in[5];
  const void* bv = d_in[6];
  const void* Wo = d_in[7];
  const void* bo = d_in[8];
  float* out = (float*)d_out;

  const size_t NTC = (size_t)Bb * Tt * Cc;   // 4.19M elements
  const size_t CC = (size_t)Cc * Cc;         // 1.05M elements

  char* wsb = (char*)d_ws;
  int* flag = (int*)wsb;                     // 256 B header
  u16* Qb = (u16*)(wsb + 256);               // [B,H,T,D] 8 MB
  u16* Kb = Qb + NTC;
  u16* Vb = Kb + NTC;
  u16* Yb = Vb + NTC;                        // [B*T][C] 8 MB
  u16* Xb = Yb + NTC;                        // bf16 X
  u16* Wqb = Xb + NTC;                       // bf16 weights
  u16* Wkb = Wqb + CC;
  u16* Wvb = Wkb + CC;
  u16* Wob = Wvb + CC;

  hipLaunchKernelGGL(detect_dtype, dim3(1), dim3(256), 0, stream, (const u16*)x, flag);
  hipLaunchKernelGGL(convert_all, dim3(512, 5), dim3(256), 0, stream,
                     x, Wq, Wk, Wv, Wo, Xb, Wqb, Wkb, Wvb, Wob, flag);
  hipLaunchKernelGGL(qkv_gemm, dim3(8, 32, 3), dim3(256), 0, stream,
                     Xb, Wqb, Wkb, Wvb, bq, bk, bv, Qb, Kb, Vb, flag);
  float* attOut = out + NTC;                 // y occupies first B*T*C floats
  hipLaunchKernelGGL(attn_kernel, dim3(256), dim3(512), 0, stream,
                     Qb, Kb, Vb, attOut, Yb);
  hipLaunchKernelGGL(out_gemm, dim3(8, 32, 1), dim3(256), 0, stream,
                     Yb, Wob, bo, out, flag);
}

// Round 5
// 706.513 us; speedup vs baseline: 1.0639x; 1.0639x over previous
//
#include <hip/hip_runtime.h>

#define DI __device__ __forceinline__

typedef __attribute__((ext_vector_type(8))) short short8;
typedef __attribute__((ext_vector_type(4))) float floatx4;
typedef unsigned short u16;

// ---- constants ----
#define Bb 2
#define Tt 2048
#define Cc 1024
#define Hh 16
#define Dd 64
// base-2 softmax: s2 = (q.k) * (1/sqrt(64)) * log2(e)
#define C1 0.1803368801111244f
#define NEGBIG (-1e30f)

DI float bf2f(u16 u) { union { unsigned int i; float f; } v; v.i = ((unsigned int)u) << 16; return v.f; }
DI u16 f2bf(float f) {
  union { float f; unsigned int i; } v; v.f = f;
  unsigned int i = v.i;
  unsigned int r = i + 0x7fffu + ((i >> 16) & 1u);  // RNE
  return (u16)(r >> 16);
}

DI floatx4 mfma16(short8 a, short8 b, floatx4 c) {
  return __builtin_amdgcn_mfma_f32_16x16x32_bf16(a, b, c, 0, 0, 0);
}

// async global->LDS, 16B per lane. LDS dest = wave-uniform base + lane*16 (linear!).
DI void gload16(const u16* g, u16* l) {
  __builtin_amdgcn_global_load_lds(
      (const __attribute__((address_space(1))) unsigned int*)(g),
      (__attribute__((address_space(3))) unsigned int*)(l), 16, 0, 0);
}

// load 8 consecutive elements (element offset eoff) as 8 bf16 packed in uint4
DI uint4 load8(const void* p, size_t eoff, int isbf) {
  if (isbf) {
    return *(const uint4*)((const u16*)p + eoff);
  } else {
    const float* f = (const float*)p + eoff;
    float4 a = *(const float4*)f;
    float4 b = *(const float4*)(f + 4);
    union { uint4 u; u16 s[8]; } r;
    r.s[0] = f2bf(a.x); r.s[1] = f2bf(a.y); r.s[2] = f2bf(a.z); r.s[3] = f2bf(a.w);
    r.s[4] = f2bf(b.x); r.s[5] = f2bf(b.y); r.s[6] = f2bf(b.z); r.s[7] = f2bf(b.w);
    return r.u;
  }
}

DI float loadb(const void* p, int i, int isbf) {
  return isbf ? bf2f(((const u16*)p)[i]) : ((const float*)p)[i];
}

// ============================================================
// dtype detector (inputs only): sample even u16 indices of x.
// ============================================================
__global__ void detect_dtype(const u16* __restrict__ x, int* __restrict__ flag) {
  __shared__ int cnt[256];
  int c = 0;
  for (int i = threadIdx.x; i < 4096; i += 256) {
    unsigned u = x[2 * i];
    unsigned e = (u >> 7) & 0xFFu;
    c += (e == 0u || (e >= 100u && e <= 150u)) ? 1 : 0;
  }
  cnt[threadIdx.x] = c;
  __syncthreads();
  for (int s = 128; s > 0; s >>= 1) {
    if ((int)threadIdx.x < s) cnt[threadIdx.x] += cnt[threadIdx.x + s];
    __syncthreads();
  }
  if (threadIdx.x == 0) *flag = (cnt[0] > 2458) ? 1 : 0;
}

// ============================================================
// one-shot convert to bf16 workspace: X (4.19M), Wq/Wk/Wv/Wo (1.05M each)
// ============================================================
__global__ __launch_bounds__(256) void convert_all(
    const void* __restrict__ x,
    const void* __restrict__ wq, const void* __restrict__ wk,
    const void* __restrict__ wv, const void* __restrict__ wo,
    u16* __restrict__ xb,
    u16* __restrict__ wqb, u16* __restrict__ wkb,
    u16* __restrict__ wvb, u16* __restrict__ wob,
    const int* __restrict__ flagp) {
  const int isbf = *flagp;
  const void* src;
  u16* dst;
  size_t n;
  switch (blockIdx.y) {
    case 0: src = x;  dst = xb;  n = (size_t)Bb * Tt * Cc; break;
    case 1: src = wq; dst = wqb; n = (size_t)Cc * Cc; break;
    case 2: src = wk; dst = wkb; n = (size_t)Cc * Cc; break;
    case 3: src = wv; dst = wvb; n = (size_t)Cc * Cc; break;
    default: src = wo; dst = wob; n = (size_t)Cc * Cc; break;
  }
  size_t i8 = ((size_t)blockIdx.x * 256 + threadIdx.x) * 8;
  size_t step = (size_t)gridDim.x * 256 * 8;
  for (; i8 < n; i8 += step) {
    uint4 v = load8(src, i8, isbf);
    *(uint4*)(dst + i8) = v;
  }
}

// ============================================================
// GEMM-BT (m97 structure): Out[m,n] = sum_k A[m,k] * W[n,k] + bias[n]
// ============================================================
__global__ __launch_bounds__(256) void qkv_gemm(
    const u16* __restrict__ Xb,
    const u16* __restrict__ Wqb, const u16* __restrict__ Wkb, const u16* __restrict__ Wvb,
    const void* __restrict__ bq, const void* __restrict__ bk, const void* __restrict__ bv,
    u16* __restrict__ Qb, u16* __restrict__ Kb, u16* __restrict__ Vb,
    const int* __restrict__ flagp) {
  __shared__ __align__(16) u16 As[128 * 32];
  __shared__ __align__(16) u16 Bs[128 * 32];
  const int isbf = *flagp;
  const int z = blockIdx.z;
  const u16* W = (z == 0) ? Wqb : (z == 1) ? Wkb : Wvb;
  const void* bias = (z == 0) ? bq : (z == 1) ? bk : bv;
  u16* Out = (z == 0) ? Qb : (z == 1) ? Kb : Vb;

  const int m0 = blockIdx.y * 128, n0 = blockIdx.x * 128;
  const int tid = threadIdx.x;
  const int w = tid >> 6, lane = tid & 63, quad = lane >> 4, l15 = lane & 15;
  const int wm = w >> 1, wn = w & 1;

  floatx4 acc[4][4];
#pragma unroll
  for (int a = 0; a < 4; ++a)
#pragma unroll
    for (int b2 = 0; b2 < 4; ++b2) acc[a][b2] = (floatx4){0.f, 0.f, 0.f, 0.f};

  const int s0 = w * 128 + lane, s1 = s0 + 64;
  const int rA0 = s0 >> 2, c0 = (s0 & 3) * 8;
  const int rA1 = s1 >> 2, c1 = (s1 & 3) * 8;
  const u16* gA0 = Xb + (size_t)(m0 + rA0) * Cc + c0;
  const u16* gA1 = Xb + (size_t)(m0 + rA1) * Cc + c1;
  const u16* gB0 = W + (size_t)(n0 + rA0) * Cc + c0;
  const u16* gB1 = W + (size_t)(n0 + rA1) * Cc + c1;
  u16* lA0 = As + w * 1024;
  u16* lA1 = As + w * 1024 + 512;
  u16* lB0 = Bs + w * 1024;
  u16* lB1 = Bs + w * 1024 + 512;

  for (int k0 = 0; k0 < Cc; k0 += 32) {
    __syncthreads();
    gload16(gA0 + k0, lA0);
    gload16(gA1 + k0, lA1);
    gload16(gB0 + k0, lB0);
    gload16(gB1 + k0, lB1);
    __syncthreads();
    short8 af[4], bfv[4];
#pragma unroll
    for (int t = 0; t < 4; ++t)
      af[t] = *(const short8*)(As + (wm * 64 + t * 16 + l15) * 32 + quad * 8);
#pragma unroll
    for (int t = 0; t < 4; ++t)
      bfv[t] = *(const short8*)(Bs + (wn * 64 + t * 16 + l15) * 32 + quad * 8);
#pragma unroll
    for (int tm = 0; tm < 4; ++tm)
#pragma unroll
      for (int tn = 0; tn < 4; ++tn) acc[tm][tn] = mfma16(af[tm], bfv[tn], acc[tm][tn]);
  }

  float bb[4];
#pragma unroll
  for (int tn = 0; tn < 4; ++tn) bb[tn] = loadb(bias, n0 + wn * 64 + tn * 16 + l15, isbf);
#pragma unroll
  for (int tm = 0; tm < 4; ++tm) {
#pragma unroll
    for (int tn = 0; tn < 4; ++tn) {
      int n = n0 + wn * 64 + tn * 16 + l15;
      int h = n >> 6, d = n & 63;
#pragma unroll
      for (int r = 0; r < 4; ++r) {
        int m = m0 + wm * 64 + tm * 16 + quad * 4 + r;
        int b = m >> 11, t = m & 2047;
        Out[(((size_t)(b * Hh + h) * Tt) + t) * Dd + d] = f2bf(acc[tm][tn][r] + bb[tn]);
      }
    }
  }
}

// out-proj (m97 structure): fp32 output to d_out
__global__ __launch_bounds__(256) void out_gemm(
    const u16* __restrict__ Y, const u16* __restrict__ Wob, const void* __restrict__ bo,
    float* __restrict__ Out, const int* __restrict__ flagp) {
  __shared__ __align__(16) u16 As[128 * 32];
  __shared__ __align__(16) u16 Bs[128 * 32];
  const int isbf = *flagp;
  const int m0 = blockIdx.y * 128, n0 = blockIdx.x * 128;
  const int tid = threadIdx.x;
  const int w = tid >> 6, lane = tid & 63, quad = lane >> 4, l15 = lane & 15;
  const int wm = w >> 1, wn = w & 1;

  floatx4 acc[4][4];
#pragma unroll
  for (int a = 0; a < 4; ++a)
#pragma unroll
    for (int b2 = 0; b2 < 4; ++b2) acc[a][b2] = (floatx4){0.f, 0.f, 0.f, 0.f};

  const int s0 = w * 128 + lane, s1 = s0 + 64;
  const int rA0 = s0 >> 2, c0 = (s0 & 3) * 8;
  const int rA1 = s1 >> 2, c1 = (s1 & 3) * 8;
  const u16* gA0 = Y + (size_t)(m0 + rA0) * Cc + c0;
  const u16* gA1 = Y + (size_t)(m0 + rA1) * Cc + c1;
  const u16* gB0 = Wob + (size_t)(n0 + rA0) * Cc + c0;
  const u16* gB1 = Wob + (size_t)(n0 + rA1) * Cc + c1;
  u16* lA0 = As + w * 1024;
  u16* lA1 = As + w * 1024 + 512;
  u16* lB0 = Bs + w * 1024;
  u16* lB1 = Bs + w * 1024 + 512;

  for (int k0 = 0; k0 < Cc; k0 += 32) {
    __syncthreads();
    gload16(gA0 + k0, lA0);
    gload16(gA1 + k0, lA1);
    gload16(gB0 + k0, lB0);
    gload16(gB1 + k0, lB1);
    __syncthreads();
    short8 af[4], bfv[4];
#pragma unroll
    for (int t = 0; t < 4; ++t)
      af[t] = *(const short8*)(As + (wm * 64 + t * 16 + l15) * 32 + quad * 8);
#pragma unroll
    for (int t = 0; t < 4; ++t)
      bfv[t] = *(const short8*)(Bs + (wn * 64 + t * 16 + l15) * 32 + quad * 8);
#pragma unroll
    for (int tm = 0; tm < 4; ++tm)
#pragma unroll
      for (int tn = 0; tn < 4; ++tn) acc[tm][tn] = mfma16(af[tm], bfv[tn], acc[tm][tn]);
  }

  float bb[4];
#pragma unroll
  for (int tn = 0; tn < 4; ++tn) bb[tn] = loadb(bo, n0 + wn * 64 + tn * 16 + l15, isbf);
#pragma unroll
  for (int tm = 0; tm < 4; ++tm)
#pragma unroll
    for (int tn = 0; tn < 4; ++tn) {
      int n = n0 + wn * 64 + tn * 16 + l15;
#pragma unroll
      for (int r = 0; r < 4; ++r) {
        int m = m0 + wm * 64 + tm * 16 + quad * 4 + r;
        Out[(size_t)m * Cc + n] = acc[tm][tn][r] + bb[tn];
      }
    }
}

// ============================================================
// Attention v6: one WG (512 thr, 8 waves) per SINGLE 128-row q-tile.
// 512 WGs, LDS 46 KB -> 3 WGs/CU (6 waves/SIMD) for cross-WG latency hiding.
// K LDS-staged (v2 inner loop, proven faster than direct-global),
// per-lane pass-1 stats, V prefetched to regs one block early.
// Big tiles dispatch first (qt = 15 - id>>5).
// ============================================================
__global__ __launch_bounds__(512) void attn_kernel(
    const u16* __restrict__ Qbuf, const u16* __restrict__ Kbuf, const u16* __restrict__ Vbuf,
    float* __restrict__ Att, u16* __restrict__ Ybuf) {
  __shared__ __align__(16) u16 Ks[128 * 72];
  __shared__ __align__(16) u16 Vts[64 * 136];
  __shared__ __align__(16) u16 Ps[8 * 16 * 40];

  const int id = blockIdx.x;
  const int qt = 15 - (id >> 5);   // big q-tiles first
  const int hb = id & 31;          // (b,h)
  const int b = hb >> 4, h = hb & 15;

  const int tid = threadIdx.x;
  const int w = tid >> 6, lane = tid & 63, quad = lane >> 4, l15 = lane & 15;

  const size_t headoff = (size_t)(b * Hh + h) * Tt * Dd;
  const u16* Qh = Qbuf + headoff;
  const u16* Kh = Kbuf + headoff;
  const u16* Vh = Vbuf + headoff;
  float* attO = Att + (size_t)(b * Hh + h) * Tt * Tt;
  u16* Psw = Ps + w * 640;

  const int q0 = qt * 128;
  const int qw = q0 + w * 16;      // wave's first q-row

  // V staging geometry: thread covers V row vrow (key), cols [vcb, vcb+16)
  const int vrow = tid >> 2, vcb = (tid & 3) * 16;

  short8 aq0 = *(const short8*)(Qh + (size_t)(qw + l15) * Dd + quad * 8);
  short8 aq1 = *(const short8*)(Qh + (size_t)(qw + l15) * Dd + 32 + quad * 8);

  float m4[4], l4[4];
#pragma unroll
  for (int r = 0; r < 4; ++r) { m4[r] = NEGBIG; l4[r] = 0.f; }

  // ---------- pass 1: stats (K staged in LDS; per-lane online stats) ----------
  for (int c = 0; c <= qt; ++c) {
    const int kb = c * 128;
    __syncthreads();
#pragma unroll
    for (int i = 0; i < 2; ++i) {
      int slot = tid + i * 512;
      int rr = slot >> 3, g = slot & 7;
      *(uint4*)(Ks + rr * 72 + g * 8) = *(const uint4*)(Kh + (size_t)(kb + rr) * Dd + g * 8);
    }
    __syncthreads();

    floatx4 s[8];
#pragma unroll
    for (int kt = 0; kt < 8; ++kt) {
      short8 b0 = *(const short8*)(Ks + (kt * 16 + l15) * 72 + quad * 8);
      short8 b1 = *(const short8*)(Ks + (kt * 16 + l15) * 72 + 32 + quad * 8);
      floatx4 t = (floatx4){0.f, 0.f, 0.f, 0.f};
      t = mfma16(aq0, b0, t);
      t = mfma16(aq1, b1, t);
      s[kt] = t;
    }
    const bool partial = (kb + 127 > qw);
#pragma unroll
    for (int r = 0; r < 4; ++r) {
      const int qi = qw + quad * 4 + r;
      float e[8];
      float bm = NEGBIG;
#pragma unroll
      for (int kt = 0; kt < 8; ++kt) {
        float s2 = s[kt][r] * C1;
        if (partial) {
          int key = kb + kt * 16 + l15;
          s2 = (key <= qi) ? s2 : NEGBIG;
        }
        e[kt] = s2;
        bm = fmaxf(bm, s2);
      }
      float mn = fmaxf(m4[r], bm);
      float sum = 0.f;
#pragma unroll
      for (int kt = 0; kt < 8; ++kt) sum += exp2f(e[kt] - mn);
      l4[r] = l4[r] * exp2f(m4[r] - mn) + sum;
      m4[r] = mn;
    }
  }
  // merge (m,l) across the 16 lanes of each row group
#pragma unroll
  for (int r = 0; r < 4; ++r) {
    float m = m4[r], l = l4[r];
#pragma unroll
    for (int off = 1; off <= 8; off <<= 1) {
      float mo = __shfl_xor(m, off, 64);
      float lo = __shfl_xor(l, off, 64);
      float mn = fmaxf(m, mo);
      l = l * exp2f(m - mn) + lo * exp2f(mo - mn);
      m = mn;
    }
    m4[r] = m; l4[r] = l;
  }
  float lrec[4];
#pragma unroll
  for (int r = 0; r < 4; ++r) lrec[r] = 1.0f / l4[r];

  // ---------- pass 2: write att fp32, accumulate y ----------
  floatx4 yacc[4];
#pragma unroll
  for (int dt = 0; dt < 4; ++dt) yacc[dt] = (floatx4){0.f, 0.f, 0.f, 0.f};

  // V(0) prefetch into regs
  uint4 va = *(const uint4*)(Vh + (size_t)vrow * Dd + vcb);
  uint4 vb = *(const uint4*)(Vh + (size_t)vrow * Dd + vcb + 8);

  for (int c = 0; c <= qt; ++c) {
    const int kb = c * 128;
    __syncthreads();   // readers of Ks/Vts from iter c-1 are done
    // stage K(c)
#pragma unroll
    for (int i = 0; i < 2; ++i) {
      int slot = tid + i * 512;
      int rr = slot >> 3, g = slot & 7;
      *(uint4*)(Ks + rr * 72 + g * 8) = *(const uint4*)(Kh + (size_t)(kb + rr) * Dd + g * 8);
    }
    // write V(c) regs -> Vts (transposed)
    {
      union { uint4 u; u16 sv[8]; } cv;
      cv.u = va;
#pragma unroll
      for (int j = 0; j < 8; ++j) Vts[(vcb + j) * 136 + vrow] = cv.sv[j];
      cv.u = vb;
#pragma unroll
      for (int j = 0; j < 8; ++j) Vts[(vcb + 8 + j) * 136 + vrow] = cv.sv[j];
    }
    // prefetch V(c+1) into regs (a full compute phase to land)
    if (c < qt) {
      va = *(const uint4*)(Vh + (size_t)(kb + 128 + vrow) * Dd + vcb);
      vb = *(const uint4*)(Vh + (size_t)(kb + 128 + vrow) * Dd + vcb + 8);
    }
    __syncthreads();   // staging visible

    floatx4 s[8];
#pragma unroll
    for (int kt = 0; kt < 8; ++kt) {
      short8 b0 = *(const short8*)(Ks + (kt * 16 + l15) * 72 + quad * 8);
      short8 b1 = *(const short8*)(Ks + (kt * 16 + l15) * 72 + 32 + quad * 8);
      floatx4 t = (floatx4){0.f, 0.f, 0.f, 0.f};
      t = mfma16(aq0, b0, t);
      t = mfma16(aq1, b1, t);
      s[kt] = t;
    }

    const bool partial = (kb + 127 > qw);
#pragma unroll
    for (int ks = 0; ks < 4; ++ks) {
#pragma unroll
      for (int kk = 0; kk < 2; ++kk) {
        const int kt = ks * 2 + kk;
#pragma unroll
        for (int r = 0; r < 4; ++r) {
          const int row = quad * 4 + r;
          const int qi = qw + row;
          const int key = kb + kt * 16 + l15;
          float p = exp2f(fminf(s[kt][r] * C1 - m4[r], 0.f)) * lrec[r];
          if (partial && key > qi) p = 0.f;
          attO[(size_t)qi * Tt + key] = p;          // fp32 att output
          Psw[row * 40 + kk * 16 + l15] = f2bf(p);  // bf16 for PV MFMA
        }
      }
      short8 ap = *(const short8*)(Psw + l15 * 40 + quad * 8);
#pragma unroll
      for (int dt = 0; dt < 4; ++dt) {
        short8 bv = *(const short8*)(Vts + (dt * 16 + l15) * 136 + ks * 32 + quad * 8);
        yacc[dt] = mfma16(ap, bv, yacc[dt]);
      }
    }
  }

  // fully masked blocks: zero-fill (no barriers)
  {
    uint4 z; z.x = 0u; z.y = 0u; z.z = 0u; z.w = 0u;
    for (int c = qt + 1; c < 16; ++c) {
      const int kb = c * 128;
#pragma unroll
      for (int i = 0; i < 8; ++i) {
        int slot = tid + i * 512;
        int row = slot >> 5, g = slot & 31;
        *(uint4*)(attO + (size_t)(q0 + row) * Tt + kb + g * 4) = z;
      }
    }
  }

  // y epilogue: wave's 16 rows x 64 d
#pragma unroll
  for (int dt = 0; dt < 4; ++dt) {
#pragma unroll
    for (int r = 0; r < 4; ++r) {
      const int qi = qw + quad * 4 + r;
      Ybuf[(size_t)(b * Tt + qi) * Cc + h * Dd + dt * 16 + l15] = f2bf(yacc[dt][r]);
    }
  }
}

extern "C" void kernel_launch(void* const* d_in, const int* in_sizes, int n_in,
                              void* d_out, int out_size, void* d_ws, size_t ws_size,
                              hipStream_t stream) {
  const void* x  = d_in[0];
  const void* Wq = d_in[1];
  const void* bq = d_in[2];
  const void* Wk = d_in[3];
  const void* bk = d_in[4];
  const void* Wv = d_in[5];
  const void* bv = d_in[6];
  const void* Wo = d_in[7];
  const void* bo = d_in[8];
  float* out = (float*)d_out;

  const size_t NTC = (size_t)Bb * Tt * Cc;   // 4.19M elements
  const size_t CC = (size_t)Cc * Cc;         // 1.05M elements

  char* wsb = (char*)d_ws;
  int* flag = (int*)wsb;                     // 256 B header
  u16* Qb = (u16*)(wsb + 256);               // [B,H,T,D] 8 MB
  u16* Kb = Qb + NTC;
  u16* Vb = Kb + NTC;
  u16* Yb = Vb + NTC;                        // [B*T][C] 8 MB
  u16* Xb = Yb + NTC;                        // bf16 X
  u16* Wqb = Xb + NTC;                       // bf16 weights
  u16* Wkb = Wqb + CC;
  u16* Wvb = Wkb + CC;
  u16* Wob = Wvb + CC;

  hipLaunchKernelGGL(detect_dtype, dim3(1), dim3(256), 0, stream, (const u16*)x, flag);
  hipLaunchKernelGGL(convert_all, dim3(512, 5), dim3(256), 0, stream,
                     x, Wq, Wk, Wv, Wo, Xb, Wqb, Wkb, Wvb, Wob, flag);
  hipLaunchKernelGGL(qkv_gemm, dim3(8, 32, 3), dim3(256), 0, stream,
                     Xb, Wqb, Wkb, Wvb, bq, bk, bv, Qb, Kb, Vb, flag);
  float* attOut = out + NTC;                 // y occupies first B*T*C floats
  hipLaunchKernelGGL(attn_kernel, dim3(512), dim3(512), 0, stream,
                     Qb, Kb, Vb, attOut, Yb);
  hipLaunchKernelGGL(out_gemm, dim3(8, 32, 1), dim3(256), 0, stream,
                     Yb, Wob, bo, out, flag);
}